// Round 8
// baseline (7866.507 us; speedup 1.0000x reference)
//
#include <hip/hip_runtime.h>

#define BATCHES 16
#define NG 2048
#define FDIM 1024
#define EPG 65536
#define NTOT (BATCHES*NG)      // 32768
#define ETOT (BATCHES*EPG)     // 1048576
#define STEPS 64
#define NBLK 512
#define NTHR 512               // 2 blocks/CU x 8 waves = 16 waves/CU (~50% occ)
#define WAVES (NTHR/64)        // 8
#define BLK_PER_BATCH (NBLK/BATCHES)          // 32
#define ROWS_PER_BLK (NG/BLK_PER_BATCH)       // 64
#define EDGE_PER_BLK (ETOT/NBLK)              // 2048

// ws layout — byte-identical to the verified round-0/5/7 kernel:
#define WS_XB0   0
#define WS_XB1   (NTOT)
#define WS_PRED  (2*NTOT)
#define WS_COEF  (3*NTOT)
#define WS_QUAD  (3*NTOT + 2*BATCHES*FDIM)
#define WS_LIN   (WS_QUAD + 2*BATCHES)
#define WS_MINR  (WS_LIN + 2*BATCHES)          // u64 cells
#define WS_BAR   (WS_MINR + 2*BATCHES)         // u64 cells: [arrive, gen]

__device__ __forceinline__ double ld_ag(const double* p) {
    return __hip_atomic_load(p, __ATOMIC_RELAXED, __HIP_MEMORY_SCOPE_AGENT);
}
__device__ __forceinline__ void st_ag(double* p, double v) {
    __hip_atomic_store(p, v, __ATOMIC_RELAXED, __HIP_MEMORY_SCOPE_AGENT);
}
__device__ __forceinline__ unsigned long long ldu64_ag(const unsigned long long* p) {
    return __hip_atomic_load(p, __ATOMIC_RELAXED, __HIP_MEMORY_SCOPE_AGENT);
}
__device__ __forceinline__ void stu64_ag(unsigned long long* p, unsigned long long v) {
    __hip_atomic_store(p, v, __ATOMIC_RELAXED, __HIP_MEMORY_SCOPE_AGENT);
}

// Lean grid barrier (hand-rolled atomics; PLAIN launch — co-residency is
// guaranteed by physical capacity: 2 blocks/CU x ~27KB = 53KB <= 160KB LDS,
// 16 waves/CU <= 32).  NEVER use hipLaunchCooperativeKernel here: its
// occupancy pre-check silently rejects LDS-heavy variants (rounds 2-4,6).
__device__ __forceinline__ void grid_barrier(unsigned long long* bar,
                                             unsigned long long g, int tid) {
    asm volatile("s_waitcnt vmcnt(0)" ::: "memory");  // all my LLC-path ops performed
    __syncthreads();
    if (tid == 0) {
        unsigned long long old = __hip_atomic_fetch_add(
            &bar[0], 1ULL, __ATOMIC_RELAXED, __HIP_MEMORY_SCOPE_AGENT);
        if (old == (unsigned long long)NBLK * g - 1ULL) {
            stu64_ag(&bar[1], g);
        } else {
            while (ldu64_ag(&bar[1]) < g) __builtin_amdgcn_s_sleep(2);
        }
    }
    __syncthreads();
}

__device__ __forceinline__ double block_reduce_sum(double v, double* s_red) {
    for (int off = 32; off > 0; off >>= 1)
        v += __shfl_down(v, off, 64);
    __syncthreads();
    int lane = threadIdx.x & 63;
    int wave = threadIdx.x >> 6;
    if (lane == 0) s_red[wave] = v;
    __syncthreads();
    double s = 0.0;
    #pragma unroll
    for (int w = 0; w < WAVES; ++w) s += s_red[w];
    return s;
}

__global__ __launch_bounds__(NTHR, 4)   // 4 waves/EU -> VGPR cap 128 (have ~84)
void GradSolver_58102317580919_kernel(
    const float* __restrict__ x_start,
    const float* __restrict__ rhs,
    const float* __restrict__ proj,
    const float* __restrict__ q,
    const float* __restrict__ obj_solution,
    const int*   __restrict__ edge_index,
    const float* __restrict__ edge_weight,
    float* __restrict__ out,                // [NTOT bestx][B best][B*STEPS gaps]
    void* __restrict__ wsv)
{
    double* ws = (double*)wsv;
    double* xb[2] = { ws + WS_XB0, ws + WS_XB1 };
    double* pred  = ws + WS_PRED;
    double* coef  = ws + WS_COEF;                    // [2][B*F]
    double* quad  = ws + WS_QUAD;                    // [2][16]
    double* lin   = ws + WS_LIN;                     // [2][16]
    unsigned long long* minr = (unsigned long long*)(ws + WS_MINR); // [2][16]
    unsigned long long* bar  = (unsigned long long*)(ws + WS_BAR);

    const int tid   = threadIdx.x;
    const int bid   = blockIdx.x;
    const int batch = bid / BLK_PER_BATCH;
    const int row_base = batch * NG + (bid % BLK_PER_BATCH) * ROWS_PER_BLK;
    const int nbase = batch * NG;
    const int lane  = tid & 63;
    const int wave  = tid >> 6;

    const unsigned long long DINF = 0x7FF0000000000000ULL;

    // LDS: 16K (s_xp) + 8K (s_coef) + 1.5K + ~100B = ~26.7 KB -> 2 blocks/CU.
    __shared__ double s_d[ROWS_PER_BLK];
    __shared__ double s_x[ROWS_PER_BLK];
    __shared__ double s_pred[ROWS_PER_BLK];
    __shared__ double s_coef[FDIM];
    __shared__ double s_xp[NG];                  // batch-wide x_k (alpha folded in)
    __shared__ double s_red[WAVES];
    __shared__ double s_bestobj;

    unsigned long long g = 0;
    double tau = 1.0;

    // ---- P0: zero accumulators (LLC path; barrier region pre-zeroed by memset) ----
    if (tid < 64) st_ag(&coef[bid*64 + tid], 0.0);   // 2*16384 / 512 = 64 each
    if (bid == 0 && tid < 16) {
        st_ag(&quad[tid], 0.0);      st_ag(&quad[16+tid], 0.0);
        st_ag(&lin[tid],  0.0);      st_ag(&lin[16+tid],  0.0);
        stu64_ag(&minr[tid], DINF);  stu64_ag(&minr[16+tid], DINF);
    }
    if (tid == 0) s_bestobj = __longlong_as_double((long long)DINF);
    grid_barrier(bar, ++g, tid);

    for (int k = 0; k <= STEPS; ++k) {
        const int p  = k & 1;        // this step's accumulation parity
        const int pp = 1 - p;        // previous step's parity
        // ================= Phase CA =================
        double alpha = 0.0;
        if (k > 0) {
            unsigned long long m = ldu64_ag(&minr[pp*16 + batch]);
            alpha = fmin(__longlong_as_double((long long)m), 1.0) * 0.995;
        }
        double xv = 0.0;
        if (tid < ROWS_PER_BLK) {
            xv = (k == 0) ? (double)x_start[row_base + tid]
                          : s_x[tid] + alpha * s_pred[tid];
            s_x[tid] = xv;
            st_ag(&xb[p][row_base + tid], xv);
            if (k < STEPS)
                s_d[tid] = -xv + (double)rhs[row_base + tid] + 0.1 * tau / (xv + tau);
        }
        tau = fmax(tau * 0.5, 1e-5);

        // stage batch-wide x_k -> LDS, coalesced (alpha folded; identical
        // per-endpoint arithmetic to the verified kernel)
        if (k == 0) {
            #pragma unroll
            for (int j = 0; j < NG/NTHR; ++j) {
                int i = tid + j*NTHR;
                s_xp[i] = (double)x_start[nbase + i];
            }
        } else {
            const double* xprev = xb[pp];
            #pragma unroll
            for (int j = 0; j < NG/NTHR; ++j) {
                int i = tid + j*NTHR;
                s_xp[i] = ld_ag(&xprev[nbase + i]) + alpha * ld_ag(&pred[nbase + i]);
            }
        }

        // resets (all barrier-separated from their readers/writers):
        if (k >= 1 && tid < 32) st_ag(&coef[pp*(BATCHES*FDIM) + bid*32 + tid], 0.0);
        if (k < STEPS && bid == 0 && tid < 16) stu64_ag(&minr[p*16 + tid], DINF);

        __syncthreads();   // s_xp (and s_d) complete

        // lin += q . x_k  (all 64 rows live in wave 0)
        if (tid < 64) {
            double lp = (double)q[row_base + tid] * xv;
            for (int off = 32; off > 0; off >>= 1)
                lp += __shfl_down(lp, off, 64);
            if (tid == 0) unsafeAtomicAdd(&lin[p*16 + batch], lp);
        }

        // quad += w * x_k[s] * x_k[d]  (edge stream from global; endpoints from LDS)
        {
            const int e0 = bid * EDGE_PER_BLK;
            double qp = 0.0;
            #pragma unroll
            for (int j = 0; j < EDGE_PER_BLK/NTHR; ++j) {
                int e  = e0 + tid + j*NTHR;
                int si = edge_index[e];
                int di = edge_index[ETOT + e];
                qp += (double)edge_weight[e] * s_xp[si - nbase] * s_xp[di - nbase];
            }
            double qs = block_reduce_sum(qp, s_red);
            if (tid == 0) unsafeAtomicAdd(&quad[p*16 + batch], qs);
        }

        // coef += P^T d   (own rows; 512 threads -> float2 per thread per row)
        if (k < STEPS) {
            double a0 = 0.0, a1 = 0.0;
            const float2* P2 = (const float2*)(proj + (size_t)row_base * FDIM);
            #pragma unroll 8
            for (int r = 0; r < ROWS_PER_BLK; ++r) {
                float2 pv = P2[r*(FDIM/2) + tid];
                double dv = s_d[r];
                a0 += (double)pv.x * dv;
                a1 += (double)pv.y * dv;
            }
            double* cf = coef + p*(BATCHES*FDIM) + batch*FDIM + 2*tid;
            unsafeAtomicAdd(cf+0, a0);
            unsafeAtomicAdd(cf+1, a1);
        }
        grid_barrier(bar, ++g, tid);

        // ================= Phase B =================
        double cur = 0.5 * ld_ag(&quad[p*16 + batch]) + ld_ag(&lin[p*16 + batch]);
        double bo  = s_bestobj;
        bool better = cur < bo;
        double nb2 = better ? cur : bo;
        __syncthreads();
        if (tid == 0) s_bestobj = nb2;

        if ((bid % BLK_PER_BATCH) == 0 && tid == 0) {
            double opt = (double)obj_solution[batch];
            double gap = fabs((opt - nb2)/opt);
            if (k >= 1)     out[NTOT + BATCHES + batch*STEPS + (k-1)] = (float)gap;
            if (k == STEPS) out[NTOT + batch] = (float)gap;
        }
        if (better && tid < ROWS_PER_BLK)
            out[row_base + tid] = (float)s_x[tid];

        if (k == STEPS) break;

        if (bid == 0 && tid < 16) {     // zero next step's obj accumulators
            st_ag(&quad[pp*16 + tid], 0.0);
            st_ag(&lin[pp*16 + tid],  0.0);
        }

        // stage coef -> LDS
        #pragma unroll
        for (int j = 0; j < FDIM/NTHR; ++j)
            s_coef[tid + NTHR*j] =
                ld_ag(&coef[p*(BATCHES*FDIM) + batch*FDIM + tid + NTHR*j]);
        __syncthreads();

        // pred = P coef  (own rows: 8 waves x 8 rows), ratio min
        {
            double c[16];
            #pragma unroll
            for (int j = 0; j < 4; ++j) {
                int f = 4*(lane + 64*j);
                c[4*j+0] = s_coef[f+0]; c[4*j+1] = s_coef[f+1];
                c[4*j+2] = s_coef[f+2]; c[4*j+3] = s_coef[f+3];
            }
            double wmin = 1e300;
            for (int i = 0; i < ROWS_PER_BLK/WAVES; ++i) {
                int r  = wave * (ROWS_PER_BLK/WAVES) + i;
                int gr = row_base + r;
                const float4* Pr = (const float4*)(proj + (size_t)gr * FDIM);
                double dot = 0.0;
                #pragma unroll
                for (int j = 0; j < 4; ++j) {
                    float4 pv = Pr[lane + 64*j];
                    dot += (double)pv.x*c[4*j+0] + (double)pv.y*c[4*j+1]
                         + (double)pv.z*c[4*j+2] + (double)pv.w*c[4*j+3];
                }
                for (int off = 32; off > 0; off >>= 1)
                    dot += __shfl_down(dot, off, 64);
                if (lane == 0) {
                    s_pred[r] = dot;
                    st_ag(&pred[gr], dot);
                    if (dot < 0.0) wmin = fmin(wmin, s_x[r] / (-dot));
                }
            }
            if (lane == 0)
                atomicMin(&minr[p*16 + batch], (unsigned long long)__double_as_longlong(wmin));
        }
        grid_barrier(bar, ++g, tid);
    }
}

extern "C" void kernel_launch(void* const* d_in, const int* in_sizes, int n_in,
                              void* d_out, int out_size, void* d_ws, size_t ws_size,
                              hipStream_t stream) {
    const float* x_start      = (const float*)d_in[0];
    const float* rhs          = (const float*)d_in[1];
    const float* proj         = (const float*)d_in[2];
    const float* q            = (const float*)d_in[3];
    const float* obj_solution = (const float*)d_in[4];
    const int*   edge_index   = (const int*)d_in[5];
    const float* edge_weight  = (const float*)d_in[6];
    float* out = (float*)d_out;
    void* ws   = d_ws;

    // zero the barrier cells (arrive, gen) — ws is poisoned 0xAA each launch
    hipMemsetAsync((char*)d_ws + (size_t)WS_BAR * 8, 0, 16, stream);

    // PLAIN launch (see barrier comment).
    hipLaunchKernelGGL(GradSolver_58102317580919_kernel,
                       dim3(NBLK), dim3(NTHR), 0, stream,
                       x_start, rhs, proj, q, obj_solution,
                       edge_index, edge_weight, out, ws);
}

// Round 9
// 6132.701 us; speedup vs baseline: 1.2827x; 1.2827x over previous
//
#include <hip/hip_runtime.h>

#define BATCHES 16
#define NG 2048
#define FDIM 1024
#define EPG 65536
#define NTOT (BATCHES*NG)      // 32768
#define ETOT (BATCHES*EPG)     // 1048576
#define STEPS 64
#define NBLK 512
#define NTHR 512               // 2 blocks/CU x 8 waves = 16 waves/CU (~50% occ)
#define WAVES (NTHR/64)        // 8
#define BLK_PER_BATCH (NBLK/BATCHES)          // 32
#define ROWS_PER_BLK (NG/BLK_PER_BATCH)       // 64
#define EDGE_PER_BLK (ETOT/NBLK)              // 2048

// ws layout — byte-identical to the verified round-0/5/7 kernel.
// (WS_BAR cells retained in layout but unused: barriers moved to g_bbar symbol.)
#define WS_XB0   0
#define WS_XB1   (NTOT)
#define WS_PRED  (2*NTOT)
#define WS_COEF  (3*NTOT)
#define WS_QUAD  (3*NTOT + 2*BATCHES*FDIM)
#define WS_LIN   (WS_QUAD + 2*BATCHES)
#define WS_MINR  (WS_LIN + 2*BATCHES)          // u64 cells
#define WS_BAR   (WS_MINR + 2*BATCHES)         // u64 cells (legacy, unused)

// Per-batch barrier state: [batch][0]=arrive, [batch][1]=gen, padded to 64B.
// Device symbol (not ws) — zeroed via hipMemsetAsync each launch.
__device__ unsigned long long g_bbar[BATCHES][8];

__device__ __forceinline__ double ld_ag(const double* p) {
    return __hip_atomic_load(p, __ATOMIC_RELAXED, __HIP_MEMORY_SCOPE_AGENT);
}
__device__ __forceinline__ void st_ag(double* p, double v) {
    __hip_atomic_store(p, v, __ATOMIC_RELAXED, __HIP_MEMORY_SCOPE_AGENT);
}
__device__ __forceinline__ unsigned long long ldu64_ag(const unsigned long long* p) {
    return __hip_atomic_load(p, __ATOMIC_RELAXED, __HIP_MEMORY_SCOPE_AGENT);
}
__device__ __forceinline__ void stu64_ag(unsigned long long* p, unsigned long long v) {
    __hip_atomic_store(p, v, __ATOMIC_RELAXED, __HIP_MEMORY_SCOPE_AGENT);
}

// Per-batch barrier: only the 32 blocks of one batch sync (batches are fully
// independent — quad/lin/minr/coef/outputs are all per-batch). 16x fewer
// same-address atomic arrives than the grid barrier, private cacheline per
// batch, and stragglers only stall their own batch. PLAIN launch only
// (hipLaunchCooperativeKernel's occupancy pre-check silently rejects
// LDS-heavy variants — rounds 2-4,6).
__device__ __forceinline__ void batch_barrier(unsigned long long* bb,
                                              unsigned long long g, int tid) {
    asm volatile("s_waitcnt vmcnt(0)" ::: "memory");  // my LLC-path ops performed
    __syncthreads();
    if (tid == 0) {
        unsigned long long old = __hip_atomic_fetch_add(
            &bb[0], 1ULL, __ATOMIC_RELAXED, __HIP_MEMORY_SCOPE_AGENT);
        if (old == (unsigned long long)BLK_PER_BATCH * g - 1ULL) {
            stu64_ag(&bb[1], g);
        } else {
            while (ldu64_ag(&bb[1]) < g) __builtin_amdgcn_s_sleep(2);
        }
    }
    __syncthreads();
}

__device__ __forceinline__ double block_reduce_sum(double v, double* s_red) {
    for (int off = 32; off > 0; off >>= 1)
        v += __shfl_down(v, off, 64);
    __syncthreads();
    int lane = threadIdx.x & 63;
    int wave = threadIdx.x >> 6;
    if (lane == 0) s_red[wave] = v;
    __syncthreads();
    double s = 0.0;
    #pragma unroll
    for (int w = 0; w < WAVES; ++w) s += s_red[w];
    return s;
}

__global__ __launch_bounds__(NTHR, 4)   // 4 waves/EU -> VGPR cap 128 (have ~64)
void GradSolver_58102317580919_kernel(
    const float* __restrict__ x_start,
    const float* __restrict__ rhs,
    const float* __restrict__ proj,
    const float* __restrict__ q,
    const float* __restrict__ obj_solution,
    const int*   __restrict__ edge_index,
    const float* __restrict__ edge_weight,
    float* __restrict__ out,                // [NTOT bestx][B best][B*STEPS gaps]
    void* __restrict__ wsv)
{
    double* ws = (double*)wsv;
    double* xb[2] = { ws + WS_XB0, ws + WS_XB1 };
    double* pred  = ws + WS_PRED;
    double* coef  = ws + WS_COEF;                    // [2][B*F]
    double* quad  = ws + WS_QUAD;                    // [2][16]
    double* lin   = ws + WS_LIN;                     // [2][16]
    unsigned long long* minr = (unsigned long long*)(ws + WS_MINR); // [2][16]

    const int tid   = threadIdx.x;
    const int bid   = blockIdx.x;
    const int batch = bid / BLK_PER_BATCH;
    const int lbid  = bid % BLK_PER_BATCH;
    const int row_base = batch * NG + lbid * ROWS_PER_BLK;
    const int nbase = batch * NG;
    const int lane  = tid & 63;
    const int wave  = tid >> 6;

    unsigned long long* bb = &g_bbar[batch][0];

    const unsigned long long DINF = 0x7FF0000000000000ULL;

    // LDS: 16K (s_xp) + 8K (s_coef) + 1.5K + ~100B = ~26.7 KB -> 2 blocks/CU.
    __shared__ double s_d[ROWS_PER_BLK];
    __shared__ double s_x[ROWS_PER_BLK];
    __shared__ double s_pred[ROWS_PER_BLK];
    __shared__ double s_coef[FDIM];
    __shared__ double s_xp[NG];                  // batch-wide x_k (alpha folded in)
    __shared__ double s_red[WAVES];
    __shared__ double s_bestobj;

    unsigned long long g = 0;
    double tau = 1.0;

    // ---- P0: zero THIS BATCH's accumulators (batch-local) ----
    if (tid < 32) {
        st_ag(&coef[0*(BATCHES*FDIM) + batch*FDIM + lbid*32 + tid], 0.0);
        st_ag(&coef[1*(BATCHES*FDIM) + batch*FDIM + lbid*32 + tid], 0.0);
    }
    if (lbid == 0 && tid == 0) {
        st_ag(&quad[batch], 0.0);      st_ag(&quad[16+batch], 0.0);
        st_ag(&lin[batch],  0.0);      st_ag(&lin[16+batch],  0.0);
        stu64_ag(&minr[batch], DINF);  stu64_ag(&minr[16+batch], DINF);
    }
    if (tid == 0) s_bestobj = __longlong_as_double((long long)DINF);
    batch_barrier(bb, ++g, tid);

    for (int k = 0; k <= STEPS; ++k) {
        const int p  = k & 1;        // this step's accumulation parity
        const int pp = 1 - p;        // previous step's parity
        // ================= Phase CA =================
        double alpha = 0.0;
        if (k > 0) {
            unsigned long long m = ldu64_ag(&minr[pp*16 + batch]);
            alpha = fmin(__longlong_as_double((long long)m), 1.0) * 0.995;
        }
        double xv = 0.0;
        if (tid < ROWS_PER_BLK) {
            xv = (k == 0) ? (double)x_start[row_base + tid]
                          : s_x[tid] + alpha * s_pred[tid];
            s_x[tid] = xv;
            st_ag(&xb[p][row_base + tid], xv);
            if (k < STEPS)
                s_d[tid] = -xv + (double)rhs[row_base + tid] + 0.1 * tau / (xv + tau);
        }
        tau = fmax(tau * 0.5, 1e-5);

        // stage batch-wide x_k -> LDS, coalesced (alpha folded; identical
        // per-endpoint arithmetic to the verified kernel)
        if (k == 0) {
            #pragma unroll
            for (int j = 0; j < NG/NTHR; ++j) {
                int i = tid + j*NTHR;
                s_xp[i] = (double)x_start[nbase + i];
            }
        } else {
            const double* xprev = xb[pp];
            #pragma unroll
            for (int j = 0; j < NG/NTHR; ++j) {
                int i = tid + j*NTHR;
                s_xp[i] = ld_ag(&xprev[nbase + i]) + alpha * ld_ag(&pred[nbase + i]);
            }
        }

        // resets (batch-local; all barrier-separated from readers/writers):
        if (k >= 1 && tid < 32)
            st_ag(&coef[pp*(BATCHES*FDIM) + batch*FDIM + lbid*32 + tid], 0.0);
        if (k < STEPS && lbid == 0 && tid == 0)
            stu64_ag(&minr[p*16 + batch], DINF);

        __syncthreads();   // s_xp (and s_d) complete

        // lin += q . x_k  (all 64 rows live in wave 0)
        if (tid < 64) {
            double lp = (double)q[row_base + tid] * xv;
            for (int off = 32; off > 0; off >>= 1)
                lp += __shfl_down(lp, off, 64);
            if (tid == 0) unsafeAtomicAdd(&lin[p*16 + batch], lp);
        }

        // quad += w * x_k[s] * x_k[d]  (edge stream from global; endpoints from LDS)
        {
            const int e0 = bid * EDGE_PER_BLK;
            double qp = 0.0;
            #pragma unroll
            for (int j = 0; j < EDGE_PER_BLK/NTHR; ++j) {
                int e  = e0 + tid + j*NTHR;
                int si = edge_index[e];
                int di = edge_index[ETOT + e];
                qp += (double)edge_weight[e] * s_xp[si - nbase] * s_xp[di - nbase];
            }
            double qs = block_reduce_sum(qp, s_red);
            if (tid == 0) unsafeAtomicAdd(&quad[p*16 + batch], qs);
        }

        // coef += P^T d   (own rows; 512 threads -> float2 per thread per row)
        if (k < STEPS) {
            double a0 = 0.0, a1 = 0.0;
            const float2* P2 = (const float2*)(proj + (size_t)row_base * FDIM);
            #pragma unroll 8
            for (int r = 0; r < ROWS_PER_BLK; ++r) {
                float2 pv = P2[r*(FDIM/2) + tid];
                double dv = s_d[r];
                a0 += (double)pv.x * dv;
                a1 += (double)pv.y * dv;
            }
            double* cf = coef + p*(BATCHES*FDIM) + batch*FDIM + 2*tid;
            unsafeAtomicAdd(cf+0, a0);
            unsafeAtomicAdd(cf+1, a1);
        }
        batch_barrier(bb, ++g, tid);

        // ================= Phase B =================
        double cur = 0.5 * ld_ag(&quad[p*16 + batch]) + ld_ag(&lin[p*16 + batch]);
        double bo  = s_bestobj;
        bool better = cur < bo;
        double nb2 = better ? cur : bo;
        __syncthreads();
        if (tid == 0) s_bestobj = nb2;

        if (lbid == 0 && tid == 0) {
            double opt = (double)obj_solution[batch];
            double gap = fabs((opt - nb2)/opt);
            if (k >= 1)     out[NTOT + BATCHES + batch*STEPS + (k-1)] = (float)gap;
            if (k == STEPS) out[NTOT + batch] = (float)gap;
        }
        if (better && tid < ROWS_PER_BLK)
            out[row_base + tid] = (float)s_x[tid];

        if (k == STEPS) break;

        if (lbid == 0 && tid == 0) {    // zero next step's obj accumulators
            st_ag(&quad[pp*16 + batch], 0.0);
            st_ag(&lin[pp*16 + batch],  0.0);
        }

        // stage coef -> LDS
        #pragma unroll
        for (int j = 0; j < FDIM/NTHR; ++j)
            s_coef[tid + NTHR*j] =
                ld_ag(&coef[p*(BATCHES*FDIM) + batch*FDIM + tid + NTHR*j]);
        __syncthreads();

        // pred = P coef  (own rows: 8 waves x 8 rows), ratio min
        {
            double c[16];
            #pragma unroll
            for (int j = 0; j < 4; ++j) {
                int f = 4*(lane + 64*j);
                c[4*j+0] = s_coef[f+0]; c[4*j+1] = s_coef[f+1];
                c[4*j+2] = s_coef[f+2]; c[4*j+3] = s_coef[f+3];
            }
            double wmin = 1e300;
            for (int i = 0; i < ROWS_PER_BLK/WAVES; ++i) {
                int r  = wave * (ROWS_PER_BLK/WAVES) + i;
                int gr = row_base + r;
                const float4* Pr = (const float4*)(proj + (size_t)gr * FDIM);
                double dot = 0.0;
                #pragma unroll
                for (int j = 0; j < 4; ++j) {
                    float4 pv = Pr[lane + 64*j];
                    dot += (double)pv.x*c[4*j+0] + (double)pv.y*c[4*j+1]
                         + (double)pv.z*c[4*j+2] + (double)pv.w*c[4*j+3];
                }
                for (int off = 32; off > 0; off >>= 1)
                    dot += __shfl_down(dot, off, 64);
                if (lane == 0) {
                    s_pred[r] = dot;
                    st_ag(&pred[gr], dot);
                    if (dot < 0.0) wmin = fmin(wmin, s_x[r] / (-dot));
                }
            }
            if (lane == 0)
                atomicMin(&minr[p*16 + batch], (unsigned long long)__double_as_longlong(wmin));
        }
        batch_barrier(bb, ++g, tid);
    }
}

extern "C" void kernel_launch(void* const* d_in, const int* in_sizes, int n_in,
                              void* d_out, int out_size, void* d_ws, size_t ws_size,
                              hipStream_t stream) {
    const float* x_start      = (const float*)d_in[0];
    const float* rhs          = (const float*)d_in[1];
    const float* proj         = (const float*)d_in[2];
    const float* q            = (const float*)d_in[3];
    const float* obj_solution = (const float*)d_in[4];
    const int*   edge_index   = (const int*)d_in[5];
    const float* edge_weight  = (const float*)d_in[6];
    float* out = (float*)d_out;
    void* ws   = d_ws;

    // zero per-batch barrier state (device symbol — no ws-layout risk)
    void* bbar_ptr = nullptr;
    hipGetSymbolAddress(&bbar_ptr, HIP_SYMBOL(g_bbar));
    hipMemsetAsync(bbar_ptr, 0, sizeof(unsigned long long) * BATCHES * 8, stream);

    // PLAIN launch (see batch_barrier comment).
    hipLaunchKernelGGL(GradSolver_58102317580919_kernel,
                       dim3(NBLK), dim3(NTHR), 0, stream,
                       x_start, rhs, proj, q, obj_solution,
                       edge_index, edge_weight, out, ws);
}

// Round 10
// 4525.012 us; speedup vs baseline: 1.7385x; 1.3553x over previous
//
#include <hip/hip_runtime.h>

#define BATCHES 16
#define NG 2048
#define FDIM 1024
#define EPG 65536
#define NTOT (BATCHES*NG)      // 32768
#define ETOT (BATCHES*EPG)     // 1048576
#define STEPS 64
#define NBLK 512
#define NTHR 512               // 2 blocks/CU x 8 waves = 16 waves/CU (~50% occ)
#define WAVES (NTHR/64)        // 8
#define BLK_PER_BATCH (NBLK/BATCHES)          // 32
#define ROWS_PER_BLK (NG/BLK_PER_BATCH)       // 64
#define EDGE_PER_BLK (ETOT/NBLK)              // 2048
#define EDGES_PER_THR (EDGE_PER_BLK/NTHR)     // 4

// ws layout — byte-identical to the verified round-0/5/7 kernel.
#define WS_XB0   0
#define WS_XB1   (NTOT)
#define WS_PRED  (2*NTOT)
#define WS_COEF  (3*NTOT)
#define WS_QUAD  (3*NTOT + 2*BATCHES*FDIM)
#define WS_LIN   (WS_QUAD + 2*BATCHES)
#define WS_MINR  (WS_LIN + 2*BATCHES)          // u64 cells
#define WS_BAR   (WS_MINR + 2*BATCHES)         // u64 cells (legacy, unused)

// Per-batch barrier state: [batch][0]=arrive, [batch][1]=gen, padded to 64B.
__device__ unsigned long long g_bbar[BATCHES][8];

__device__ __forceinline__ double ld_ag(const double* p) {
    return __hip_atomic_load(p, __ATOMIC_RELAXED, __HIP_MEMORY_SCOPE_AGENT);
}
__device__ __forceinline__ void st_ag(double* p, double v) {
    __hip_atomic_store(p, v, __ATOMIC_RELAXED, __HIP_MEMORY_SCOPE_AGENT);
}
__device__ __forceinline__ unsigned long long ldu64_ag(const unsigned long long* p) {
    return __hip_atomic_load(p, __ATOMIC_RELAXED, __HIP_MEMORY_SCOPE_AGENT);
}
__device__ __forceinline__ void stu64_ag(unsigned long long* p, unsigned long long v) {
    __hip_atomic_store(p, v, __ATOMIC_RELAXED, __HIP_MEMORY_SCOPE_AGENT);
}

// Per-batch barrier (32 participants). PLAIN launch only — cooperative
// launch's occupancy pre-check silently rejects LDS-heavy variants
// (rounds 2-4,6). Co-residency by capacity: 2 blocks/CU x 26.7KB LDS.
__device__ __forceinline__ void batch_barrier(unsigned long long* bb,
                                              unsigned long long g, int tid) {
    asm volatile("s_waitcnt vmcnt(0)" ::: "memory");
    __syncthreads();
    if (tid == 0) {
        unsigned long long old = __hip_atomic_fetch_add(
            &bb[0], 1ULL, __ATOMIC_RELAXED, __HIP_MEMORY_SCOPE_AGENT);
        if (old == (unsigned long long)BLK_PER_BATCH * g - 1ULL) {
            stu64_ag(&bb[1], g);
        } else {
            while (ldu64_ag(&bb[1]) < g) __builtin_amdgcn_s_sleep(2);
        }
    }
    __syncthreads();
}

__device__ __forceinline__ double block_reduce_sum(double v, double* s_red) {
    for (int off = 32; off > 0; off >>= 1)
        v += __shfl_down(v, off, 64);
    __syncthreads();
    int lane = threadIdx.x & 63;
    int wave = threadIdx.x >> 6;
    if (lane == 0) s_red[wave] = v;
    __syncthreads();
    double s = 0.0;
    #pragma unroll
    for (int w = 0; w < WAVES; ++w) s += s_red[w];
    return s;
}

__global__ __launch_bounds__(NTHR, 4)   // VGPR cap 128; 2 blocks/CU -> 16 waves/CU
void GradSolver_58102317580919_kernel(
    const float* __restrict__ x_start,
    const float* __restrict__ rhs,
    const float* __restrict__ proj,
    const float* __restrict__ q,
    const float* __restrict__ obj_solution,
    const int*   __restrict__ edge_index,
    const float* __restrict__ edge_weight,
    float* __restrict__ out,                // [NTOT bestx][B best][B*STEPS gaps]
    void* __restrict__ wsv)
{
    double* ws = (double*)wsv;
    double* xb[2] = { ws + WS_XB0, ws + WS_XB1 };
    double* pred  = ws + WS_PRED;
    double* coef  = ws + WS_COEF;                    // [2][B*F]
    double* quad  = ws + WS_QUAD;                    // [2][16]
    double* lin   = ws + WS_LIN;                     // [2][16]
    unsigned long long* minr = (unsigned long long*)(ws + WS_MINR); // [2][16]

    const int tid   = threadIdx.x;
    const int bid   = blockIdx.x;
    const int batch = bid / BLK_PER_BATCH;
    const int lbid  = bid % BLK_PER_BATCH;
    const int row_base = batch * NG + lbid * ROWS_PER_BLK;
    const int nbase = batch * NG;
    const int lane  = tid & 63;
    const int wave  = tid >> 6;

    unsigned long long* bb = &g_bbar[batch][0];

    const unsigned long long DINF = 0x7FF0000000000000ULL;

    // LDS: 16K (s_xp) + 8K (s_coef) + 1.5K + ~100B = ~26.7 KB -> 2 blocks/CU.
    __shared__ double s_d[ROWS_PER_BLK];
    __shared__ double s_x[ROWS_PER_BLK];
    __shared__ double s_pred[ROWS_PER_BLK];
    __shared__ double s_coef[FDIM];
    __shared__ double s_xp[NG];                  // batch-wide x_k (alpha folded in)
    __shared__ double s_red[WAVES];
    __shared__ double s_bestobj;

    unsigned long long g = 0;
    double tau = 1.0;

    // ---- edges -> registers ONCE (immutable; 4/thread) ----
    unsigned epk[EDGES_PER_THR];
    float    ew[EDGES_PER_THR];
    {
        const int e0 = bid * EDGE_PER_BLK;
        #pragma unroll
        for (int j = 0; j < EDGES_PER_THR; ++j) {
            int e = e0 + tid + j*NTHR;
            unsigned si = (unsigned)(edge_index[e]        - nbase);  // < 2048
            unsigned di = (unsigned)(edge_index[ETOT + e] - nbase);
            epk[j] = si | (di << 11);
            ew[j]  = edge_weight[e];
        }
    }

    // ---- P0: zero THIS BATCH's accumulators (batch-local) ----
    if (tid < 32) {
        st_ag(&coef[0*(BATCHES*FDIM) + batch*FDIM + lbid*32 + tid], 0.0);
        st_ag(&coef[1*(BATCHES*FDIM) + batch*FDIM + lbid*32 + tid], 0.0);
    }
    if (lbid == 0 && tid == 0) {
        st_ag(&quad[batch], 0.0);      st_ag(&quad[16+batch], 0.0);
        st_ag(&lin[batch],  0.0);      st_ag(&lin[16+batch],  0.0);
        stu64_ag(&minr[batch], DINF);  stu64_ag(&minr[16+batch], DINF);
    }
    if (tid == 0) s_bestobj = __longlong_as_double((long long)DINF);
    batch_barrier(bb, ++g, tid);

    for (int k = 0; k <= STEPS; ++k) {
        const int p  = k & 1;        // this step's accumulation parity
        const int pp = 1 - p;        // previous step's parity
        // ================= Phase CA =================
        double alpha = 0.0;
        if (k > 0) {
            unsigned long long m = ldu64_ag(&minr[pp*16 + batch]);
            alpha = fmin(__longlong_as_double((long long)m), 1.0) * 0.995;
        }
        // early-issue staging loads (independent of the s_x/s_d chain)
        double sxr[NG/NTHR], spr[NG/NTHR];
        if (k > 0) {
            const double* xprev = xb[pp];
            #pragma unroll
            for (int j = 0; j < NG/NTHR; ++j) {
                sxr[j] = ld_ag(&xprev[nbase + tid + j*NTHR]);
                spr[j] = ld_ag(&pred[nbase + tid + j*NTHR]);
            }
        }
        double xv = 0.0;
        if (tid < ROWS_PER_BLK) {
            xv = (k == 0) ? (double)x_start[row_base + tid]
                          : s_x[tid] + alpha * s_pred[tid];
            s_x[tid] = xv;
            st_ag(&xb[p][row_base + tid], xv);
            if (k < STEPS)
                s_d[tid] = -xv + (double)rhs[row_base + tid] + 0.1 * tau / (xv + tau);
        }
        tau = fmax(tau * 0.5, 1e-5);

        // stage batch-wide x_k -> LDS (alpha folded; arithmetic identical
        // to the verified per-endpoint expression)
        if (k == 0) {
            #pragma unroll
            for (int j = 0; j < NG/NTHR; ++j) {
                int i = tid + j*NTHR;
                s_xp[i] = (double)x_start[nbase + i];
            }
        } else {
            #pragma unroll
            for (int j = 0; j < NG/NTHR; ++j)
                s_xp[tid + j*NTHR] = sxr[j] + alpha * spr[j];
        }

        // resets (batch-local; barrier-separated from readers/writers):
        if (k >= 1 && tid < 32)
            st_ag(&coef[pp*(BATCHES*FDIM) + batch*FDIM + lbid*32 + tid], 0.0);
        if (k < STEPS && lbid == 0 && tid == 0)
            stu64_ag(&minr[p*16 + batch], DINF);

        __syncthreads();   // s_xp (and s_d) complete

        // lin += q . x_k  (all 64 rows live in wave 0)
        if (tid < 64) {
            double lp = (double)q[row_base + tid] * xv;
            for (int off = 32; off > 0; off >>= 1)
                lp += __shfl_down(lp, off, 64);
            if (tid == 0) unsafeAtomicAdd(&lin[p*16 + batch], lp);
        }

        // quad += w * x_k[s] * x_k[d]  (edges in registers, endpoints in LDS)
        {
            double qp = 0.0;
            #pragma unroll
            for (int j = 0; j < EDGES_PER_THR; ++j) {
                unsigned pk = epk[j];
                qp += (double)ew[j] * s_xp[pk & 2047u] * s_xp[(pk >> 11) & 2047u];
            }
            double qs = block_reduce_sum(qp, s_red);
            if (tid == 0) unsafeAtomicAdd(&quad[p*16 + batch], qs);
        }

        // coef += P^T d   (own rows; float2 per thread per row)
        if (k < STEPS) {
            double a0 = 0.0, a1 = 0.0;
            const float2* P2 = (const float2*)(proj + (size_t)row_base * FDIM);
            #pragma unroll 8
            for (int r = 0; r < ROWS_PER_BLK; ++r) {
                float2 pv = P2[r*(FDIM/2) + tid];
                double dv = s_d[r];
                a0 += (double)pv.x * dv;
                a1 += (double)pv.y * dv;
            }
            double* cf = coef + p*(BATCHES*FDIM) + batch*FDIM + 2*tid;
            unsafeAtomicAdd(cf+0, a0);
            unsafeAtomicAdd(cf+1, a1);
        }
        batch_barrier(bb, ++g, tid);

        // ========= Phase B + pred (pred first — it gates the next step) =========
        // issue all independent LLC loads immediately after the barrier:
        double cv0 = 0.0, cv1 = 0.0;
        if (k < STEPS) {
            cv0 = ld_ag(&coef[p*(BATCHES*FDIM) + batch*FDIM + tid]);
            cv1 = ld_ag(&coef[p*(BATCHES*FDIM) + batch*FDIM + tid + NTHR]);
        }
        double qv = ld_ag(&quad[p*16 + batch]);
        double lv = ld_ag(&lin[p*16 + batch]);

        double wmin = 1e300;
        if (k < STEPS) {
            s_coef[tid]        = cv0;
            s_coef[tid + NTHR] = cv1;
            __syncthreads();
            double c[16];
            #pragma unroll
            for (int j = 0; j < 4; ++j) {
                int f = 4*(lane + 64*j);
                c[4*j+0] = s_coef[f+0]; c[4*j+1] = s_coef[f+1];
                c[4*j+2] = s_coef[f+2]; c[4*j+3] = s_coef[f+3];
            }
            for (int i = 0; i < ROWS_PER_BLK/WAVES; ++i) {
                int r  = wave * (ROWS_PER_BLK/WAVES) + i;
                int gr = row_base + r;
                const float4* Pr = (const float4*)(proj + (size_t)gr * FDIM);
                double dot = 0.0;
                #pragma unroll
                for (int j = 0; j < 4; ++j) {
                    float4 pv = Pr[lane + 64*j];
                    dot += (double)pv.x*c[4*j+0] + (double)pv.y*c[4*j+1]
                         + (double)pv.z*c[4*j+2] + (double)pv.w*c[4*j+3];
                }
                for (int off = 32; off > 0; off >>= 1)
                    dot += __shfl_down(dot, off, 64);
                if (lane == 0) {
                    s_pred[r] = dot;
                    st_ag(&pred[gr], dot);
                    if (dot < 0.0) wmin = fmin(wmin, s_x[r] / (-dot));
                }
            }
            if (lane == 0) s_red[wave] = wmin;   // per-wave min -> LDS
        }

        // objective bookkeeping (off the pred critical path)
        double cur = 0.5 * qv + lv;
        double bo  = s_bestobj;
        bool better = cur < bo;
        double nb2 = better ? cur : bo;
        __syncthreads();   // uniform: covers s_red writes + s_bestobj reads
        if (tid == 0) s_bestobj = nb2;
        if (k < STEPS && tid == 0) {
            double m8 = s_red[0];
            #pragma unroll
            for (int w = 1; w < WAVES; ++w) m8 = fmin(m8, s_red[w]);
            atomicMin(&minr[p*16 + batch],
                      (unsigned long long)__double_as_longlong(m8));  // 1 per block
        }
        if (k < STEPS && lbid == 0 && tid == 0) {   // zero next step's accumulators
            st_ag(&quad[pp*16 + batch], 0.0);
            st_ag(&lin[pp*16 + batch],  0.0);
        }
        if (lbid == 0 && tid == 0) {
            double opt = (double)obj_solution[batch];
            double gap = fabs((opt - nb2)/opt);
            if (k >= 1)     out[NTOT + BATCHES + batch*STEPS + (k-1)] = (float)gap;
            if (k == STEPS) out[NTOT + batch] = (float)gap;
        }
        if (better && tid < ROWS_PER_BLK)
            out[row_base + tid] = (float)s_x[tid];

        if (k == STEPS) break;
        batch_barrier(bb, ++g, tid);
    }
}

extern "C" void kernel_launch(void* const* d_in, const int* in_sizes, int n_in,
                              void* d_out, int out_size, void* d_ws, size_t ws_size,
                              hipStream_t stream) {
    const float* x_start      = (const float*)d_in[0];
    const float* rhs          = (const float*)d_in[1];
    const float* proj         = (const float*)d_in[2];
    const float* q            = (const float*)d_in[3];
    const float* obj_solution = (const float*)d_in[4];
    const int*   edge_index   = (const int*)d_in[5];
    const float* edge_weight  = (const float*)d_in[6];
    float* out = (float*)d_out;
    void* ws   = d_ws;

    // zero per-batch barrier state (device symbol — no ws-layout risk)
    void* bbar_ptr = nullptr;
    hipGetSymbolAddress(&bbar_ptr, HIP_SYMBOL(g_bbar));
    hipMemsetAsync(bbar_ptr, 0, sizeof(unsigned long long) * BATCHES * 8, stream);

    // PLAIN launch (see batch_barrier comment).
    hipLaunchKernelGGL(GradSolver_58102317580919_kernel,
                       dim3(NBLK), dim3(NTHR), 0, stream,
                       x_start, rhs, proj, q, obj_solution,
                       edge_index, edge_weight, out, ws);
}